// Round 13
// baseline (164.330 us; speedup 1.0000x reference)
//
#include <hip/hip_runtime.h>
#include <math.h>

#define BB      2
#define CC      512
#define NN_TOK  4096
#define HEADS   8
#define DHEAD   64
#define HID     512
#define GROUPS  32
#define CPG     (CC / GROUPS)
#define EPS     1e-5f

typedef __bf16 bf16x8 __attribute__((ext_vector_type(8)));
typedef float  f32x4  __attribute__((ext_vector_type(4)));
typedef float  f32x2  __attribute__((ext_vector_type(2)));
typedef float  f32x16 __attribute__((ext_vector_type(16)));
typedef int    i32x8  __attribute__((ext_vector_type(8)));

static __device__ __forceinline__ unsigned short f2bf(float f) {
  __bf16 h = (__bf16)f;
  return __builtin_bit_cast(unsigned short, h);
}
static __device__ __forceinline__ float bf2f(unsigned short u) {
  unsigned v = (unsigned)u << 16;
  return __builtin_bit_cast(float, v);
}
static __device__ __forceinline__ unsigned pk_fp8x4(float a, float b, float c, float d) {
  int lo = __builtin_amdgcn_cvt_pk_fp8_f32(a, b, 0, false);
  return (unsigned)__builtin_amdgcn_cvt_pk_fp8_f32(c, d, lo, true);
}
static __device__ __forceinline__ unsigned char f2fp8(float a) {
  return (unsigned char)(__builtin_amdgcn_cvt_pk_fp8_f32(a, a, 0, false) & 0xff);
}
// Fast exp2 for fp8-bound softmax (validated rounds 6/8), PAIRED: the FMA
// half runs as packed fp32 (v_pk_fma_f32, 2 elems/op) via elementwise_fma.
static __device__ __forceinline__ void exp2p(float a, float b,
                                             float* oa, float* ob) {
  f32x2 s = {a, b};
  f32x2 t = __builtin_elementwise_fma(
      s, (f32x2){8388608.0f, 8388608.0f},
      (f32x2){1064993216.0f, 1064993216.0f});
  *oa = __builtin_bit_cast(float, (int)t[0]);
  *ob = __builtin_bit_cast(float, (int)t[1]);
}
// 32-byte LDS fragment load (8-byte-aligned rows)
static __device__ __forceinline__ i32x8 ld_frag32(const unsigned char* p) {
  union { i32x8 v; long l[4]; } u;
  u.l[0] = *(const long*)(p + 0);
  u.l[1] = *(const long*)(p + 8);
  u.l[2] = *(const long*)(p + 16);
  u.l[3] = *(const long*)(p + 24);
  return u.v;
}
// 32-byte GLOBAL fragment load (two dwordx4)
static __device__ __forceinline__ i32x8 ld_g32(const unsigned char* p) {
  union { i32x8 v; uint4 q[2]; } u;
  u.q[0] = *(const uint4*)(p);
  u.q[1] = *(const uint4*)(p + 16);
  return u.v;
}
#define SC_ONE 0x7F7F7F7F   // E8M0 scale bytes: 127 -> 2^0 = 1.0
#define QKV_WS 32.0f        // wq/wk/wv pre-scale before fp8
#define QKV_WS_INV 0.03125f
#define WO_WS 16.0f         // wo pre-scale before fp8
#define WO_WS_INV 0.0625f

// ---------------------------------------------------------------------------
// GroupNorm stats + weight conversion, 1024 blocks (4/CU), linear weights.
// ---------------------------------------------------------------------------
__global__ __launch_bounds__(256) void gn_stats_wconv_kernel(
    const float* __restrict__ x, float2* __restrict__ part,
    const float* __restrict__ wq, const float* __restrict__ wk,
    const float* __restrict__ wv, const float* __restrict__ wo,
    unsigned char* __restrict__ wq8, unsigned char* __restrict__ wk8,
    unsigned char* __restrict__ wv8, unsigned char* __restrict__ wo8) {
  int blk = blockIdx.x;                        // 0..1023
  int t = threadIdx.x;
  {
    int wsel = blk >> 8;                       // 256 blocks per weight
    int off = (blk & 255) * 1024 + t * 4;
    const float* s = (wsel == 0) ? wq : (wsel == 1) ? wk : (wsel == 2) ? wv : wo;
    unsigned char* d = (wsel == 0) ? wq8 : (wsel == 1) ? wk8 : (wsel == 2) ? wv8 : wo8;
    float sc = (wsel < 3) ? QKV_WS : WO_WS;
    float4 a = *(const float4*)&s[off];
    *(unsigned*)&d[off] = pk_fp8x4(a.x * sc, a.y * sc, a.z * sc, a.w * sc);
  }
  const float4* __restrict__ x4 = (const float4*)(x + (size_t)blk * 4096);
  float s = 0.f, ss = 0.f;
  #pragma unroll
  for (int i = 0; i < 4; ++i) {
    float4 v = x4[t + i * 256];
    s  += v.x + v.y + v.z + v.w;
    ss += v.x * v.x + v.y * v.y + v.z * v.z + v.w * v.w;
  }
  #pragma unroll
  for (int off = 32; off >= 1; off >>= 1) {
    s  += __shfl_down(s, off, 64);
    ss += __shfl_down(ss, off, 64);
  }
  __shared__ float rs[4], rss[4];
  int wid = t >> 6, lane = t & 63;
  if (lane == 0) { rs[wid] = s; rss[wid] = ss; }
  __syncthreads();
  if (t == 0) {
    float2 o;
    o.x = rs[0] + rs[1] + rs[2] + rs[3];
    o.y = rss[0] + rss[1] + rss[2] + rss[3];
    part[blk] = o;
  }
}

// ---------------------------------------------------------------------------
// Fused GroupNorm-apply + transpose: x fp32 [b][c][tok] -> xnT8 fp8 [b][tok][c].
// Round 13: transpose-read phase VECTORIZED. Old phase read 16 scalar u16 at
// stride 144 B -> bank = (ch*288 + ...) mod 32 with 288 % 32 == 0 -> 16-way
// conflict. New: 4-tok x 4-chan micro-tile per thread = 4x ushort4 (b64)
// reads (banks spread {0,16}+2*tg, ~2-4 way) + 4 uint stores.
// ---------------------------------------------------------------------------
__global__ __launch_bounds__(256) void gn_norm_t_kernel(
    const float* __restrict__ x, const float* __restrict__ gamma,
    const float* __restrict__ beta, const float2* __restrict__ part,
    unsigned char* __restrict__ xnT8) {
  __shared__ __align__(16) unsigned short lds[64 * 72];
  __shared__ float mu4[4], rs4[4];
  int b = blockIdx.z;
  int t0 = blockIdx.x * 64, c0 = blockIdx.y * 64;
  int t = threadIdx.x;
  if (t < 4) {
    int g = (c0 >> 4) + t;
    int gi = b * GROUPS + g;
    float S = 0.f, SS = 0.f;
    #pragma unroll
    for (int k = 0; k < 16; ++k) {
      float2 p = part[gi * 16 + k];
      S += p.x; SS += p.y;
    }
    const float inv_n = 1.0f / (float)(CPG * NN_TOK);
    float mu = S * inv_n;
    float var = SS * inv_n - mu * mu;
    mu4[t] = mu;
    rs4[t] = rsqrtf(var + EPS);
  }
  __syncthreads();
  const float* __restrict__ xb = x + (size_t)b * CC * NN_TOK;
  #pragma unroll
  for (int i = 0; i < 4; ++i) {
    int f = t + i * 256;
    int row = f >> 4, c16 = f & 15;
    int c = c0 + row;
    float ga = gamma[c] * rs4[row >> 4];
    float be = beta[c] - mu4[row >> 4] * ga;
    float4 v = *(const float4*)&xb[(size_t)c * NN_TOK + t0 + c16 * 4];
    ushort4 pk;
    pk.x = f2bf(v.x * ga + be); pk.y = f2bf(v.y * ga + be);
    pk.z = f2bf(v.z * ga + be); pk.w = f2bf(v.w * ga + be);
    *(ushort4*)&lds[row * 72 + c16 * 4] = pk;
  }
  __syncthreads();
  unsigned char* __restrict__ ob = xnT8 + (size_t)b * NN_TOK * CC;
  {
    int ch4 = t & 15;                 // 4-channel group
    int tg  = t >> 4;                 // 4-token group
    union { ushort4 u; unsigned short s[4]; } v4[4];
    #pragma unroll
    for (int k = 0; k < 4; ++k)
      v4[k].u = *(const ushort4*)&lds[(ch4 * 4 + k) * 72 + tg * 4];
    #pragma unroll
    for (int k2 = 0; k2 < 4; ++k2) {
      float f0 = bf2f(v4[0].s[k2]);
      float f1 = bf2f(v4[1].s[k2]);
      float f2 = bf2f(v4[2].s[k2]);
      float f3 = bf2f(v4[3].s[k2]);
      *(unsigned*)&ob[(size_t)(t0 + tg * 4 + k2) * CC + c0 + ch4 * 4] =
          pk_fp8x4(f0, f1, f2, f3);
    }
  }
}

// ---------------------------------------------------------------------------
// Fused Q/K/V GEMM on scaled 32x32x64 f8f6f4: double-buffered LDS with
// issue-early/write-late staging (r10 config, unchanged).
// ---------------------------------------------------------------------------
__global__ __launch_bounds__(256, 3) void qkv_gemm_kernel(
    const unsigned char* __restrict__ xnT8,
    const unsigned char* __restrict__ wq8, const unsigned char* __restrict__ wk8,
    const unsigned char* __restrict__ wv8,
    const float* __restrict__ bq, const float* __restrict__ bk,
    const float* __restrict__ bv,
    unsigned char* __restrict__ qT8, unsigned char* __restrict__ kT8,
    unsigned char* __restrict__ vB8) {
  __shared__ __align__(16) unsigned char AB[2][2][128 * 72];  // [buf][A/B]
  int b = blockIdx.z;
  int y = blockIdx.y;
  int which = y >> 2, yl = y & 3;
  const unsigned char* __restrict__ W =
      (which == 0) ? wq8 : (which == 1) ? wk8 : wv8;
  const float* __restrict__ bias = (which == 0) ? bq : (which == 1) ? bk : bv;
  int m0 = yl * 128;
  int n0 = blockIdx.x * 128;
  const unsigned char* __restrict__ Bsrc = xnT8 + (size_t)b * NN_TOK * CC;
  int t = threadIdx.x, w = t >> 6, lane = t & 63;
  int wm = (w >> 1) * 64, wn = (w & 1) * 64;
  int l31 = lane & 31, q1h = lane >> 5;

  int sr0 = t >> 2, sr1 = (t + 256) >> 2, sch = t & 3;
  const unsigned char* Wa0 = &W[(size_t)(m0 + sr0) * CC + sch * 16];
  const unsigned char* Wa1 = &W[(size_t)(m0 + sr1) * CC + sch * 16];
  const unsigned char* Bb0 = &Bsrc[(size_t)(n0 + sr0) * CC + sch * 16];
  const unsigned char* Bb1 = &Bsrc[(size_t)(n0 + sr1) * CC + sch * 16];
  uint4 ra0 = *(const uint4*)(Wa0);
  uint4 ra1 = *(const uint4*)(Wa1);
  uint4 rb0 = *(const uint4*)(Bb0);
  uint4 rb1 = *(const uint4*)(Bb1);

  const f32x16 z16 = {0,0,0,0,0,0,0,0,0,0,0,0,0,0,0,0};
  f32x16 acc[2][2];
  #pragma unroll
  for (int mt = 0; mt < 2; ++mt)
    #pragma unroll
    for (int nt = 0; nt < 2; ++nt) acc[mt][nt] = z16;

  int cur = 0;
  for (int kc = 0; kc < CC; kc += 64) {
    __syncthreads();
    {
      unsigned char* As = AB[cur][0];
      unsigned char* Bs = AB[cur][1];
      unsigned char* ad0 = &As[sr0 * 72 + sch * 16];
      *(uint2*)ad0 = make_uint2(ra0.x, ra0.y);
      *(uint2*)(ad0 + 8) = make_uint2(ra0.z, ra0.w);
      unsigned char* ad1 = &As[sr1 * 72 + sch * 16];
      *(uint2*)ad1 = make_uint2(ra1.x, ra1.y);
      *(uint2*)(ad1 + 8) = make_uint2(ra1.z, ra1.w);
      unsigned char* bd0 = &Bs[sr0 * 72 + sch * 16];
      *(uint2*)bd0 = make_uint2(rb0.x, rb0.y);
      *(uint2*)(bd0 + 8) = make_uint2(rb0.z, rb0.w);
      unsigned char* bd1 = &Bs[sr1 * 72 + sch * 16];
      *(uint2*)bd1 = make_uint2(rb1.x, rb1.y);
      *(uint2*)(bd1 + 8) = make_uint2(rb1.z, rb1.w);
    }
    if (kc + 64 < CC) {               // issue next tile; completes under MFMA
      ra0 = *(const uint4*)(Wa0 + kc + 64);
      ra1 = *(const uint4*)(Wa1 + kc + 64);
      rb0 = *(const uint4*)(Bb0 + kc + 64);
      rb1 = *(const uint4*)(Bb1 + kc + 64);
    }
    __syncthreads();
    const unsigned char* As = AB[cur][0];
    const unsigned char* Bs = AB[cur][1];
    i32x8 af[2], bfm[2];
    #pragma unroll
    for (int i = 0; i < 2; ++i) {
      af[i]  = ld_frag32(&As[(wm + i * 32 + l31) * 72 + q1h * 32]);
      bfm[i] = ld_frag32(&Bs[(wn + i * 32 + l31) * 72 + q1h * 32]);
    }
    #pragma unroll
    for (int mt = 0; mt < 2; ++mt)
      #pragma unroll
      for (int nt = 0; nt < 2; ++nt)
        acc[mt][nt] = __builtin_amdgcn_mfma_scale_f32_32x32x64_f8f6f4(
            af[mt], bfm[nt], acc[mt][nt], 0, 0, 0, SC_ONE, 0, SC_ONE);
    cur ^= 1;
  }
  __syncthreads();

  if (which < 2) {
    const float sc = (which == 0) ? 0.18033688011112043f : 1.0f; // 0.125*log2e
    unsigned char* __restrict__ dstT = (which == 0) ? qT8 : kT8;
    unsigned char* buf = (unsigned char*)AB + w * 2560; // per-wave [32 tok][80 B]
    int h = (m0 + wm) >> 6;
    const size_t hbase = (size_t)(b * HEADS + h) * NN_TOK;
    #pragma unroll
    for (int p = 0; p < 2; ++p) {          // p = nt (32-token half)
      #pragma unroll
      for (int mt = 0; mt < 2; ++mt) {
        #pragma unroll
        for (int g = 0; g < 4; ++g) {
          float4 bv4 = *(const float4*)&bias[m0 + wm + mt * 32 + g * 8 + q1h * 4];
          f32x16 a = acc[mt][p];
          unsigned pk = pk_fp8x4((a[4 * g + 0] * QKV_WS_INV + bv4.x) * sc,
                                 (a[4 * g + 1] * QKV_WS_INV + bv4.y) * sc,
                                 (a[4 * g + 2] * QKV_WS_INV + bv4.z) * sc,
                                 (a[4 * g + 3] * QKV_WS_INV + bv4.w) * sc);
          *(unsigned*)&buf[l31 * 80 + mt * 32 + g * 8 + q1h * 4] = pk;
        }
      }
      #pragma unroll
      for (int it = 0; it < 2; ++it) {
        int idx = it * 64 + lane;
        int row = idx >> 2, ch = idx & 3;
        int tok = n0 + wn + p * 32 + row;
        *(uint4*)&dstT[(hbase + tok) * DHEAD + ch * 16] =
            *(const uint4*)&buf[row * 80 + ch * 16];
      }
      __syncthreads();
    }
  } else {
    unsigned char* __restrict__ dst = vB8 + (size_t)b * HID * NN_TOK;
    #pragma unroll
    for (int mt = 0; mt < 2; ++mt) {
      #pragma unroll
      for (int g = 0; g < 4; ++g) {
        float4 bv4 = *(const float4*)&bias[m0 + wm + mt * 32 + g * 8 + q1h * 4];
        float bvr[4] = {bv4.x, bv4.y, bv4.z, bv4.w};
        #pragma unroll
        for (int nt = 0; nt < 2; ++nt) {
          int tok = n0 + wn + nt * 32 + l31;
          #pragma unroll
          for (int r = 0; r < 4; ++r) {
            int m = m0 + wm + mt * 32 + g * 8 + q1h * 4 + r;
            dst[(size_t)m * NN_TOK + tok] =
                f2fp8(acc[mt][nt][4 * g + r] * QKV_WS_INV + bvr[r]);
          }
        }
      }
    }
  }
}

// ---------------------------------------------------------------------------
// Out-proj GEMM, 64m x 64n, grid (64, 8, 2) = 1024 blocks (r10 config).
// ---------------------------------------------------------------------------
__global__ __launch_bounds__(256) void outproj_kernel(
    const unsigned char* __restrict__ aoT8, const unsigned char* __restrict__ wo8,
    const float* __restrict__ bo, const float* __restrict__ x,
    float* __restrict__ out) {
  __shared__ __align__(16) unsigned char As8[2][64 * 80];
  __shared__ __align__(16) unsigned char Bs8[2][64 * 80];
  int b = blockIdx.z;
  int m0 = blockIdx.y * 64;
  int n0 = blockIdx.x * 64;
  const unsigned char* __restrict__ Bsrc = aoT8 + (size_t)b * NN_TOK * HID;
  int t = threadIdx.x, w = t >> 6, lane = t & 63;
  int wm = (w & 1) * 32, wn = (w >> 1) * 32;
  int l31 = lane & 31, q1h = lane >> 5;

  int ar = t >> 2, ach = t & 3;
  const unsigned char* pa = &wo8[(size_t)(m0 + ar) * HID + ach * 16];
  const unsigned char* pbb = &Bsrc[(size_t)(n0 + ar) * HID + ach * 16];
  uint4 ra = *(const uint4*)(pa);
  uint4 rb = *(const uint4*)(pbb);

  const f32x16 z16 = {0,0,0,0,0,0,0,0,0,0,0,0,0,0,0,0};
  f32x16 acc = z16;

  int cur = 0;
  for (int kc = 0; kc < HID; kc += 64) {
    __syncthreads();
    *(uint4*)&As8[cur][ar * 80 + ach * 16] = ra;
    *(uint4*)&Bs8[cur][ar * 80 + ach * 16] = rb;
    if (kc + 64 < HID) {
      ra = *(const uint4*)(pa + kc + 64);
      rb = *(const uint4*)(pbb + kc + 64);
    }
    __syncthreads();
    i32x8 af = ld_frag32(&As8[cur][(wm + l31) * 80 + q1h * 32]);
    i32x8 bfm = ld_frag32(&Bs8[cur][(wn + l31) * 80 + q1h * 32]);
    acc = __builtin_amdgcn_mfma_scale_f32_32x32x64_f8f6f4(
        af, bfm, acc, 0, 0, 0, SC_ONE, 0, SC_ONE);
    cur ^= 1;
  }

  const float* __restrict__ xb = x + (size_t)b * CC * NN_TOK;
  float* __restrict__ ob = out + (size_t)b * CC * NN_TOK;
  int tok = n0 + wn + l31;
  #pragma unroll
  for (int g = 0; g < 4; ++g) {
    float4 bv4 = *(const float4*)&bo[m0 + wm + g * 8 + q1h * 4];
    float bvr[4] = {bv4.x, bv4.y, bv4.z, bv4.w};
    #pragma unroll
    for (int r = 0; r < 4; ++r) {
      int m = m0 + wm + g * 8 + q1h * 4 + r;
      size_t off = (size_t)m * NN_TOK + tok;
      ob[off] = acc[4 * g + r] * WO_WS_INV + bvr[r] + xb[off];
    }
  }
}

// ---------------------------------------------------------------------------
// MFMA flash attention, round 13: r12 structure (K direct-global + XCD
// swizzle, V LDS dbuf permuted, 1 barrier/iter) with the exp FMA half packed
// (v_pk_fma_f32 pairs, -16 VALU ops/iter). No volatile asm (r6 lesson).
// ---------------------------------------------------------------------------
__global__ __launch_bounds__(512, 4) void attn_mfma_kernel(
    const unsigned char* __restrict__ qT8, const unsigned char* __restrict__ kT8,
    const unsigned char* __restrict__ vv8, unsigned char* __restrict__ aoT8) {
  __shared__ __align__(16) unsigned char kvs[2 * 9216];    // V dbuf fp8
  __shared__ __align__(16) unsigned char st8[4 * 32 * 80]; // epilogue stage fp8
  __shared__ float lbuf[128];
  // XCD-aware swizzle: lid in [0,512); xcd = lid&7 gets blocks [xcd*64, +64)
  int lid = blockIdx.x + 32 * blockIdx.y;
  int swz = (lid & 7) * 64 + (lid >> 3);
  int bh = swz >> 5;
  int b = bh >> 3, h = bh & 7;
  int i0 = (swz & 31) * 128;
  const size_t hb = (size_t)bh * NN_TOK;
  const unsigned char* __restrict__ qtg = qT8 + hb * DHEAD;
  const unsigned char* __restrict__ ktg = kT8 + hb * DHEAD;
  const unsigned char* __restrict__ vg  = vv8 + hb * DHEAD;
  int t = threadIdx.x;
  int w = t >> 6, lane = t & 63, l31 = lane & 31, q1h = lane >> 5;
  int strip = w & 3, parity = w >> 2;
  int iw = i0 + strip * 32;

  const unsigned char* qrow = qtg + (size_t)(iw + l31) * DHEAD + q1h * 32;
  uint4 qv0 = *(const uint4*)(qrow);
  uint4 qv1 = *(const uint4*)(qrow + 16);
  i32x8 qf = {(int)qv0.x, (int)qv0.y, (int)qv0.z, (int)qv0.w,
              (int)qv1.x, (int)qv1.y, (int)qv1.z, (int)qv1.w};
  i32x8 ones;                       // 32x fp8 e4m3 1.0 per lane (A = all-ones)
  #pragma unroll
  for (int i = 0; i < 8; ++i) ones[i] = 0x38383838;

  const unsigned char* kfb = ktg + (size_t)(parity * 64 + l31) * DHEAD + q1h * 32;

  int vtile = t >> 8, vrr = (t >> 2) & 63, vch = t & 3;
  const unsigned char* vga = &vg[(size_t)vrr * NN_TOK + vtile * 64 + vch * 16];
  int vbase = vtile * 4608 + vrr * 72 + 8 * (vch & 1) + 16 * (vch >> 1);

  uint4 vx = *(const uint4*)(vga);   // prologue V load for rt=0

  const f32x16 z16 = {0,0,0,0,0,0,0,0,0,0,0,0,0,0,0,0};
  f32x16 o0 = z16, o1 = z16, lacc = z16;

  int cur = 0;
  for (int rt = 0; rt < NN_TOK / 128; ++rt) {
    int j0 = rt * 128;
    {  // write-late: V tile rt into buffer cur, permuted column placement
      unsigned char* vd = kvs + cur * 9216 + vbase;
      *(uint2*)vd = make_uint2(vx.x, vx.z);          // bit2(j)=0 columns
      *(uint2*)(vd + 32) = make_uint2(vx.y, vx.w);   // bit2(j)=1 columns
    }
    if (rt + 1 < NN_TOK / 128)       // issue-early: next V tile
      vx = *(const uint4*)(vga + (rt + 1) * 128);

    // K fragments direct from global (no barrier dependency; L2-hit via swz)
    i32x8 ka0 = ld_g32(kfb + (size_t)j0 * DHEAD);
    i32x8 ka1 = ld_g32(kfb + (size_t)(j0 + 32) * DHEAD);

    __syncthreads();                 // V[cur] visible; single barrier per iter

    f32x16 s0 = __builtin_amdgcn_mfma_scale_f32_32x32x64_f8f6f4(
        ka0, qf, z16, 0, 0, 0, SC_ONE, 0, SC_ONE);
    f32x16 s1 = __builtin_amdgcn_mfma_scale_f32_32x32x64_f8f6f4(
        ka1, qf, z16, 0, 0, 0, SC_ONE, 0, SC_ONE);

    // fast exp2 (packed-FMA pairs), pack 4 fp8 per dword; l via ones-MFMA
    unsigned pk4[8];
    #pragma unroll
    for (int g = 0; g < 4; ++g) {
      float p0, p1, p2, p3;
      exp2p(s0[4 * g + 0], s0[4 * g + 1], &p0, &p1);
      exp2p(s0[4 * g + 2], s0[4 * g + 3], &p2, &p3);
      pk4[g] = pk_fp8x4(p0, p1, p2, p3);
    }
    #pragma unroll
    for (int g = 0; g < 4; ++g) {
      float p0, p1, p2, p3;
      exp2p(s1[4 * g + 0], s1[4 * g + 1], &p0, &p1);
      exp2p(s1[4 * g + 2], s1[4 * g + 3], &p2, &p3);
      pk4[4 + g] = pk_fp8x4(p0, p1, p2, p3);
    }

    // P fragment: permuted V -> lane's own packs are its B-fragment verbatim.
    i32x8 pb;
    #pragma unroll
    for (int g = 0; g < 8; ++g) pb[g] = (int)pk4[g];

    // PV + ones-l from LDS V[cur] (columns pre-permuted to match)
    const unsigned char* vsw = kvs + cur * 9216 + parity * 4608;
    i32x8 va0 = ld_frag32(&vsw[l31 * 72 + q1h * 32]);
    i32x8 va1 = ld_frag32(&vsw[(32 + l31) * 72 + q1h * 32]);
    o0 = __builtin_amdgcn_mfma_scale_f32_32x32x64_f8f6f4(
        va0, pb, o0, 0, 0, 0, SC_ONE, 0, SC_ONE);
    o1 = __builtin_amdgcn_mfma_scale_f32_32x32x64_f8f6f4(
        va1, pb, o1, 0, 0, 0, SC_ONE, 0, SC_ONE);
    lacc = __builtin_amdgcn_mfma_scale_f32_32x32x64_f8f6f4(
        ones, pb, lacc, 0, 0, 0, SC_ONE, 0, SC_ONE);
    cur ^= 1;
  }
  float lrun = lacc[0];   // all 32 C-rows equal sum_j P[j][i]

  // ---- two-phase parity combine (obuf overlays V dbuf; st8 separate) ----
  float* obuf = (float*)kvs;           // [strip][d 32][i 32] f32 = 16 KB
  __syncthreads();
  if (parity == 1) {                   // phase A: o0 (d 0..31)
    #pragma unroll
    for (int r = 0; r < 16; ++r) {
      int d = (r & 3) + 8 * (r >> 2) + 4 * q1h;
      obuf[strip * 1024 + d * 32 + l31] = o0[r];
    }
    if (q1h == 0) lbuf[strip * 32 + l31] = lrun;
  }
  __syncthreads();
  if (parity == 0) {
    lrun += lbuf[strip * 32 + l31];
    #pragma unroll
    for (int r = 0; r < 16; ++r) {
      int d = (r & 3) + 8 * (r >> 2) + 4 * q1h;
      o0[r] += obuf[strip * 1024 + d * 32 + l31];
    }
  }
  __syncthreads();
  if (parity == 1) {                   // phase B: o1 (d 32..63)
    #pragma unroll
    for (int r = 0; r < 16; ++r) {
      int d = (r & 3) + 8 * (r >> 2) + 4 * q1h;
      obuf[strip * 1024 + d * 32 + l31] = o1[r];
    }
  }
  __syncthreads();
  if (parity == 0) {
    #pragma unroll
    for (int r = 0; r < 16; ++r) {
      int d = (r & 3) + 8 * (r >> 2) + 4 * q1h;
      o1[r] += obuf[strip * 1024 + d * 32 + l31];
    }
    float inv = 1.0f / lrun;
    unsigned char* stw = st8 + strip * 2560;   // [32 i][80 B]
    #pragma unroll
    for (int dm = 0; dm < 2; ++dm) {
      #pragma unroll
      for (int g = 0; g < 4; ++g) {
        float v0 = ((dm == 0) ? o0[4 * g + 0] : o1[4 * g + 0]) * inv;
        float v1 = ((dm == 0) ? o0[4 * g + 1] : o1[4 * g + 1]) * inv;
        float v2 = ((dm == 0) ? o0[4 * g + 2] : o1[4 * g + 2]) * inv;
        float v3 = ((dm == 0) ? o0[4 * g + 3] : o1[4 * g + 3]) * inv;
        *(unsigned*)&stw[l31 * 80 + dm * 32 + g * 8 + q1h * 4] =
            pk_fp8x4(v0, v1, v2, v3);
      }
    }
    const size_t obase = (size_t)b * NN_TOK;
    #pragma unroll
    for (int it = 0; it < 4; ++it) {
      int idx = it * 64 + lane;
      int row = idx >> 3, ch = idx & 7;      // 32 rows x 8 8B-chunks
      int tok = iw + row;
      *(uint2*)&aoT8[(obase + tok) * HID + h * DHEAD + ch * 8] =
          *(const uint2*)&stw[row * 80 + ch * 8];
    }
  }
}

// ---------------------------------------------------------------------------
extern "C" void kernel_launch(void* const* d_in, const int* in_sizes, int n_in,
                              void* d_out, int out_size, void* d_ws, size_t ws_size,
                              hipStream_t stream) {
  const float* x     = (const float*)d_in[0];
  const float* gamma = (const float*)d_in[1];
  const float* beta  = (const float*)d_in[2];
  const float* wq    = (const float*)d_in[3];
  const float* bq    = (const float*)d_in[4];
  const float* wk    = (const float*)d_in[5];
  const float* bk    = (const float*)d_in[6];
  const float* wv    = (const float*)d_in[7];
  const float* bv    = (const float*)d_in[8];
  const float* wo    = (const float*)d_in[9];
  const float* bo    = (const float*)d_in[10];
  float* out = (float*)d_out;

  const size_t SZ = (size_t)BB * CC * NN_TOK;       // 4,194,304 elements
  const size_t WZ = (size_t)CC * HID;
  unsigned char* xnT8 = (unsigned char*)d_ws;       // fp8 [b][tok][c]     4 MB
  unsigned char* qT8  = xnT8 + SZ;                  // fp8 [b,h,tok,d]     4 MB
  unsigned char* kT8  = qT8 + SZ;                   // fp8                 4 MB
  unsigned char* vB8  = kT8 + SZ;                   // fp8 [b][c][tok]     4 MB
  unsigned char* aoT8 = vB8 + SZ;                   // fp8 [b][tok][hid]   4 MB
  unsigned char* wq8  = aoT8 + SZ;                  // fp8 weights (x32)
  unsigned char* wk8  = wq8 + WZ;
  unsigned char* wv8  = wk8 + WZ;
  unsigned char* wo8  = wv8 + WZ;                   // fp8 (x16)
  float2* gnpart = (float2*)(wo8 + WZ);             // 1024 float2

  gn_stats_wconv_kernel<<<dim3(1024), dim3(256), 0, stream>>>(
      x, gnpart, wq, wk, wv, wo, wq8, wk8, wv8, wo8);

  gn_norm_t_kernel<<<dim3(NN_TOK / 64, CC / 64, BB), dim3(256), 0, stream>>>(
      x, gamma, beta, gnpart, xnT8);

  qkv_gemm_kernel<<<dim3(NN_TOK / 128, 12, BB), dim3(256), 0, stream>>>(
      xnT8, wq8, wk8, wv8, bq, bk, bv, qT8, kT8, vB8);

  attn_mfma_kernel<<<dim3(NN_TOK / 128, BB * HEADS), dim3(512), 0, stream>>>(
      qT8, kT8, vB8, aoT8);

  outproj_kernel<<<dim3(NN_TOK / 64, CC / 64, BB), dim3(256), 0, stream>>>(
      aoT8, wo8, bo, x, out);
}

// Round 14
// 159.782 us; speedup vs baseline: 1.0285x; 1.0285x over previous
//
#include <hip/hip_runtime.h>
#include <math.h>

#define BB      2
#define CC      512
#define NN_TOK  4096
#define HEADS   8
#define DHEAD   64
#define HID     512
#define GROUPS  32
#define CPG     (CC / GROUPS)
#define EPS     1e-5f

typedef __bf16 bf16x8 __attribute__((ext_vector_type(8)));
typedef float  f32x4  __attribute__((ext_vector_type(4)));
typedef float  f32x16 __attribute__((ext_vector_type(16)));
typedef int    i32x8  __attribute__((ext_vector_type(8)));

static __device__ __forceinline__ unsigned short f2bf(float f) {
  __bf16 h = (__bf16)f;
  return __builtin_bit_cast(unsigned short, h);
}
static __device__ __forceinline__ float bf2f(unsigned short u) {
  unsigned v = (unsigned)u << 16;
  return __builtin_bit_cast(float, v);
}
static __device__ __forceinline__ unsigned pk_fp8x4(float a, float b, float c, float d) {
  int lo = __builtin_amdgcn_cvt_pk_fp8_f32(a, b, 0, false);
  return (unsigned)__builtin_amdgcn_cvt_pk_fp8_f32(c, d, lo, true);
}
static __device__ __forceinline__ unsigned char f2fp8(float a) {
  return (unsigned char)(__builtin_amdgcn_cvt_pk_fp8_f32(a, a, 0, false) & 0xff);
}
// Fast exp2 for fp8-bound softmax (validated rounds 6/8/12). SCALAR form —
// r13's packed-f32x2 variant regressed (vector construct + extract broke the
// FMA->cvt->pack chain scheduling).
static __device__ __forceinline__ float exp2_fast(float s) {
  float t = __builtin_fmaf(s, 8388608.0f, 1064993216.0f);
  int i = (int)t;
  return __builtin_bit_cast(float, i);
}
// 32-byte LDS fragment load (8-byte-aligned rows)
static __device__ __forceinline__ i32x8 ld_frag32(const unsigned char* p) {
  union { i32x8 v; long l[4]; } u;
  u.l[0] = *(const long*)(p + 0);
  u.l[1] = *(const long*)(p + 8);
  u.l[2] = *(const long*)(p + 16);
  u.l[3] = *(const long*)(p + 24);
  return u.v;
}
// 32-byte GLOBAL fragment load (two dwordx4)
static __device__ __forceinline__ i32x8 ld_g32(const unsigned char* p) {
  union { i32x8 v; uint4 q[2]; } u;
  u.q[0] = *(const uint4*)(p);
  u.q[1] = *(const uint4*)(p + 16);
  return u.v;
}
#define SC_ONE 0x7F7F7F7F   // E8M0 scale bytes: 127 -> 2^0 = 1.0
#define QKV_WS 32.0f        // wq/wk/wv pre-scale before fp8
#define QKV_WS_INV 0.03125f
#define WO_WS 16.0f         // wo pre-scale before fp8
#define WO_WS_INV 0.0625f

// ---------------------------------------------------------------------------
// GroupNorm stats + weight conversion, 1024 blocks (4/CU), linear weights.
// ---------------------------------------------------------------------------
__global__ __launch_bounds__(256) void gn_stats_wconv_kernel(
    const float* __restrict__ x, float2* __restrict__ part,
    const float* __restrict__ wq, const float* __restrict__ wk,
    const float* __restrict__ wv, const float* __restrict__ wo,
    unsigned char* __restrict__ wq8, unsigned char* __restrict__ wk8,
    unsigned char* __restrict__ wv8, unsigned char* __restrict__ wo8) {
  int blk = blockIdx.x;                        // 0..1023
  int t = threadIdx.x;
  {
    int wsel = blk >> 8;                       // 256 blocks per weight
    int off = (blk & 255) * 1024 + t * 4;
    const float* s = (wsel == 0) ? wq : (wsel == 1) ? wk : (wsel == 2) ? wv : wo;
    unsigned char* d = (wsel == 0) ? wq8 : (wsel == 1) ? wk8 : (wsel == 2) ? wv8 : wo8;
    float sc = (wsel < 3) ? QKV_WS : WO_WS;
    float4 a = *(const float4*)&s[off];
    *(unsigned*)&d[off] = pk_fp8x4(a.x * sc, a.y * sc, a.z * sc, a.w * sc);
  }
  const float4* __restrict__ x4 = (const float4*)(x + (size_t)blk * 4096);
  float s = 0.f, ss = 0.f;
  #pragma unroll
  for (int i = 0; i < 4; ++i) {
    float4 v = x4[t + i * 256];
    s  += v.x + v.y + v.z + v.w;
    ss += v.x * v.x + v.y * v.y + v.z * v.z + v.w * v.w;
  }
  #pragma unroll
  for (int off = 32; off >= 1; off >>= 1) {
    s  += __shfl_down(s, off, 64);
    ss += __shfl_down(ss, off, 64);
  }
  __shared__ float rs[4], rss[4];
  int wid = t >> 6, lane = t & 63;
  if (lane == 0) { rs[wid] = s; rss[wid] = ss; }
  __syncthreads();
  if (t == 0) {
    float2 o;
    o.x = rs[0] + rs[1] + rs[2] + rs[3];
    o.y = rss[0] + rss[1] + rss[2] + rss[3];
    part[blk] = o;
  }
}

// ---------------------------------------------------------------------------
// Fused GroupNorm-apply + transpose: x fp32 [b][c][tok] -> xnT8 fp8 [b][tok][c].
// Vectorized transpose-read (r13 win, kept): 4-tok x 4-chan micro-tile per
// thread = 4x ushort4 reads (~2-4 way banks, was 16-way scalar) + 4 stores.
// ---------------------------------------------------------------------------
__global__ __launch_bounds__(256) void gn_norm_t_kernel(
    const float* __restrict__ x, const float* __restrict__ gamma,
    const float* __restrict__ beta, const float2* __restrict__ part,
    unsigned char* __restrict__ xnT8) {
  __shared__ __align__(16) unsigned short lds[64 * 72];
  __shared__ float mu4[4], rs4[4];
  int b = blockIdx.z;
  int t0 = blockIdx.x * 64, c0 = blockIdx.y * 64;
  int t = threadIdx.x;
  if (t < 4) {
    int g = (c0 >> 4) + t;
    int gi = b * GROUPS + g;
    float S = 0.f, SS = 0.f;
    #pragma unroll
    for (int k = 0; k < 16; ++k) {
      float2 p = part[gi * 16 + k];
      S += p.x; SS += p.y;
    }
    const float inv_n = 1.0f / (float)(CPG * NN_TOK);
    float mu = S * inv_n;
    float var = SS * inv_n - mu * mu;
    mu4[t] = mu;
    rs4[t] = rsqrtf(var + EPS);
  }
  __syncthreads();
  const float* __restrict__ xb = x + (size_t)b * CC * NN_TOK;
  #pragma unroll
  for (int i = 0; i < 4; ++i) {
    int f = t + i * 256;
    int row = f >> 4, c16 = f & 15;
    int c = c0 + row;
    float ga = gamma[c] * rs4[row >> 4];
    float be = beta[c] - mu4[row >> 4] * ga;
    float4 v = *(const float4*)&xb[(size_t)c * NN_TOK + t0 + c16 * 4];
    ushort4 pk;
    pk.x = f2bf(v.x * ga + be); pk.y = f2bf(v.y * ga + be);
    pk.z = f2bf(v.z * ga + be); pk.w = f2bf(v.w * ga + be);
    *(ushort4*)&lds[row * 72 + c16 * 4] = pk;
  }
  __syncthreads();
  unsigned char* __restrict__ ob = xnT8 + (size_t)b * NN_TOK * CC;
  {
    int ch4 = t & 15;                 // 4-channel group
    int tg  = t >> 4;                 // 4-token group
    union { ushort4 u; unsigned short s[4]; } v4[4];
    #pragma unroll
    for (int k = 0; k < 4; ++k)
      v4[k].u = *(const ushort4*)&lds[(ch4 * 4 + k) * 72 + tg * 4];
    #pragma unroll
    for (int k2 = 0; k2 < 4; ++k2) {
      float f0 = bf2f(v4[0].s[k2]);
      float f1 = bf2f(v4[1].s[k2]);
      float f2 = bf2f(v4[2].s[k2]);
      float f3 = bf2f(v4[3].s[k2]);
      *(unsigned*)&ob[(size_t)(t0 + tg * 4 + k2) * CC + c0 + ch4 * 4] =
          pk_fp8x4(f0, f1, f2, f3);
    }
  }
}

// ---------------------------------------------------------------------------
// Fused Q/K/V GEMM on scaled 32x32x64 f8f6f4: double-buffered LDS with
// issue-early/write-late staging (r10 config, unchanged).
// ---------------------------------------------------------------------------
__global__ __launch_bounds__(256, 3) void qkv_gemm_kernel(
    const unsigned char* __restrict__ xnT8,
    const unsigned char* __restrict__ wq8, const unsigned char* __restrict__ wk8,
    const unsigned char* __restrict__ wv8,
    const float* __restrict__ bq, const float* __restrict__ bk,
    const float* __restrict__ bv,
    unsigned char* __restrict__ qT8, unsigned char* __restrict__ kT8,
    unsigned char* __restrict__ vB8) {
  __shared__ __align__(16) unsigned char AB[2][2][128 * 72];  // [buf][A/B]
  int b = blockIdx.z;
  int y = blockIdx.y;
  int which = y >> 2, yl = y & 3;
  const unsigned char* __restrict__ W =
      (which == 0) ? wq8 : (which == 1) ? wk8 : wv8;
  const float* __restrict__ bias = (which == 0) ? bq : (which == 1) ? bk : bv;
  int m0 = yl * 128;
  int n0 = blockIdx.x * 128;
  const unsigned char* __restrict__ Bsrc = xnT8 + (size_t)b * NN_TOK * CC;
  int t = threadIdx.x, w = t >> 6, lane = t & 63;
  int wm = (w >> 1) * 64, wn = (w & 1) * 64;
  int l31 = lane & 31, q1h = lane >> 5;

  int sr0 = t >> 2, sr1 = (t + 256) >> 2, sch = t & 3;
  const unsigned char* Wa0 = &W[(size_t)(m0 + sr0) * CC + sch * 16];
  const unsigned char* Wa1 = &W[(size_t)(m0 + sr1) * CC + sch * 16];
  const unsigned char* Bb0 = &Bsrc[(size_t)(n0 + sr0) * CC + sch * 16];
  const unsigned char* Bb1 = &Bsrc[(size_t)(n0 + sr1) * CC + sch * 16];
  uint4 ra0 = *(const uint4*)(Wa0);
  uint4 ra1 = *(const uint4*)(Wa1);
  uint4 rb0 = *(const uint4*)(Bb0);
  uint4 rb1 = *(const uint4*)(Bb1);

  const f32x16 z16 = {0,0,0,0,0,0,0,0,0,0,0,0,0,0,0,0};
  f32x16 acc[2][2];
  #pragma unroll
  for (int mt = 0; mt < 2; ++mt)
    #pragma unroll
    for (int nt = 0; nt < 2; ++nt) acc[mt][nt] = z16;

  int cur = 0;
  for (int kc = 0; kc < CC; kc += 64) {
    __syncthreads();
    {
      unsigned char* As = AB[cur][0];
      unsigned char* Bs = AB[cur][1];
      unsigned char* ad0 = &As[sr0 * 72 + sch * 16];
      *(uint2*)ad0 = make_uint2(ra0.x, ra0.y);
      *(uint2*)(ad0 + 8) = make_uint2(ra0.z, ra0.w);
      unsigned char* ad1 = &As[sr1 * 72 + sch * 16];
      *(uint2*)ad1 = make_uint2(ra1.x, ra1.y);
      *(uint2*)(ad1 + 8) = make_uint2(ra1.z, ra1.w);
      unsigned char* bd0 = &Bs[sr0 * 72 + sch * 16];
      *(uint2*)bd0 = make_uint2(rb0.x, rb0.y);
      *(uint2*)(bd0 + 8) = make_uint2(rb0.z, rb0.w);
      unsigned char* bd1 = &Bs[sr1 * 72 + sch * 16];
      *(uint2*)bd1 = make_uint2(rb1.x, rb1.y);
      *(uint2*)(bd1 + 8) = make_uint2(rb1.z, rb1.w);
    }
    if (kc + 64 < CC) {               // issue next tile; completes under MFMA
      ra0 = *(const uint4*)(Wa0 + kc + 64);
      ra1 = *(const uint4*)(Wa1 + kc + 64);
      rb0 = *(const uint4*)(Bb0 + kc + 64);
      rb1 = *(const uint4*)(Bb1 + kc + 64);
    }
    __syncthreads();
    const unsigned char* As = AB[cur][0];
    const unsigned char* Bs = AB[cur][1];
    i32x8 af[2], bfm[2];
    #pragma unroll
    for (int i = 0; i < 2; ++i) {
      af[i]  = ld_frag32(&As[(wm + i * 32 + l31) * 72 + q1h * 32]);
      bfm[i] = ld_frag32(&Bs[(wn + i * 32 + l31) * 72 + q1h * 32]);
    }
    #pragma unroll
    for (int mt = 0; mt < 2; ++mt)
      #pragma unroll
      for (int nt = 0; nt < 2; ++nt)
        acc[mt][nt] = __builtin_amdgcn_mfma_scale_f32_32x32x64_f8f6f4(
            af[mt], bfm[nt], acc[mt][nt], 0, 0, 0, SC_ONE, 0, SC_ONE);
    cur ^= 1;
  }
  __syncthreads();

  if (which < 2) {
    const float sc = (which == 0) ? 0.18033688011112043f : 1.0f; // 0.125*log2e
    unsigned char* __restrict__ dstT = (which == 0) ? qT8 : kT8;
    unsigned char* buf = (unsigned char*)AB + w * 2560; // per-wave [32 tok][80 B]
    int h = (m0 + wm) >> 6;
    const size_t hbase = (size_t)(b * HEADS + h) * NN_TOK;
    #pragma unroll
    for (int p = 0; p < 2; ++p) {          // p = nt (32-token half)
      #pragma unroll
      for (int mt = 0; mt < 2; ++mt) {
        #pragma unroll
        for (int g = 0; g < 4; ++g) {
          float4 bv4 = *(const float4*)&bias[m0 + wm + mt * 32 + g * 8 + q1h * 4];
          f32x16 a = acc[mt][p];
          unsigned pk = pk_fp8x4((a[4 * g + 0] * QKV_WS_INV + bv4.x) * sc,
                                 (a[4 * g + 1] * QKV_WS_INV + bv4.y) * sc,
                                 (a[4 * g + 2] * QKV_WS_INV + bv4.z) * sc,
                                 (a[4 * g + 3] * QKV_WS_INV + bv4.w) * sc);
          *(unsigned*)&buf[l31 * 80 + mt * 32 + g * 8 + q1h * 4] = pk;
        }
      }
      #pragma unroll
      for (int it = 0; it < 2; ++it) {
        int idx = it * 64 + lane;
        int row = idx >> 2, ch = idx & 3;
        int tok = n0 + wn + p * 32 + row;
        *(uint4*)&dstT[(hbase + tok) * DHEAD + ch * 16] =
            *(const uint4*)&buf[row * 80 + ch * 16];
      }
      __syncthreads();
    }
  } else {
    unsigned char* __restrict__ dst = vB8 + (size_t)b * HID * NN_TOK;
    #pragma unroll
    for (int mt = 0; mt < 2; ++mt) {
      #pragma unroll
      for (int g = 0; g < 4; ++g) {
        float4 bv4 = *(const float4*)&bias[m0 + wm + mt * 32 + g * 8 + q1h * 4];
        float bvr[4] = {bv4.x, bv4.y, bv4.z, bv4.w};
        #pragma unroll
        for (int nt = 0; nt < 2; ++nt) {
          int tok = n0 + wn + nt * 32 + l31;
          #pragma unroll
          for (int r = 0; r < 4; ++r) {
            int m = m0 + wm + mt * 32 + g * 8 + q1h * 4 + r;
            dst[(size_t)m * NN_TOK + tok] =
                f2fp8(acc[mt][nt][4 * g + r] * QKV_WS_INV + bvr[r]);
          }
        }
      }
    }
  }
}

// ---------------------------------------------------------------------------
// Out-proj GEMM, 64m x 64n, grid (64, 8, 2) = 1024 blocks (r10 config).
// ---------------------------------------------------------------------------
__global__ __launch_bounds__(256) void outproj_kernel(
    const unsigned char* __restrict__ aoT8, const unsigned char* __restrict__ wo8,
    const float* __restrict__ bo, const float* __restrict__ x,
    float* __restrict__ out) {
  __shared__ __align__(16) unsigned char As8[2][64 * 80];
  __shared__ __align__(16) unsigned char Bs8[2][64 * 80];
  int b = blockIdx.z;
  int m0 = blockIdx.y * 64;
  int n0 = blockIdx.x * 64;
  const unsigned char* __restrict__ Bsrc = aoT8 + (size_t)b * NN_TOK * HID;
  int t = threadIdx.x, w = t >> 6, lane = t & 63;
  int wm = (w & 1) * 32, wn = (w >> 1) * 32;
  int l31 = lane & 31, q1h = lane >> 5;

  int ar = t >> 2, ach = t & 3;
  const unsigned char* pa = &wo8[(size_t)(m0 + ar) * HID + ach * 16];
  const unsigned char* pbb = &Bsrc[(size_t)(n0 + ar) * HID + ach * 16];
  uint4 ra = *(const uint4*)(pa);
  uint4 rb = *(const uint4*)(pbb);

  const f32x16 z16 = {0,0,0,0,0,0,0,0,0,0,0,0,0,0,0,0};
  f32x16 acc = z16;

  int cur = 0;
  for (int kc = 0; kc < HID; kc += 64) {
    __syncthreads();
    *(uint4*)&As8[cur][ar * 80 + ach * 16] = ra;
    *(uint4*)&Bs8[cur][ar * 80 + ach * 16] = rb;
    if (kc + 64 < HID) {
      ra = *(const uint4*)(pa + kc + 64);
      rb = *(const uint4*)(pbb + kc + 64);
    }
    __syncthreads();
    i32x8 af = ld_frag32(&As8[cur][(wm + l31) * 80 + q1h * 32]);
    i32x8 bfm = ld_frag32(&Bs8[cur][(wn + l31) * 80 + q1h * 32]);
    acc = __builtin_amdgcn_mfma_scale_f32_32x32x64_f8f6f4(
        af, bfm, acc, 0, 0, 0, SC_ONE, 0, SC_ONE);
    cur ^= 1;
  }

  const float* __restrict__ xb = x + (size_t)b * CC * NN_TOK;
  float* __restrict__ ob = out + (size_t)b * CC * NN_TOK;
  int tok = n0 + wn + l31;
  #pragma unroll
  for (int g = 0; g < 4; ++g) {
    float4 bv4 = *(const float4*)&bo[m0 + wm + g * 8 + q1h * 4];
    float bvr[4] = {bv4.x, bv4.y, bv4.z, bv4.w};
    #pragma unroll
    for (int r = 0; r < 4; ++r) {
      int m = m0 + wm + g * 8 + q1h * 4 + r;
      size_t off = (size_t)m * NN_TOK + tok;
      ob[off] = acc[4 * g + r] * WO_WS_INV + bvr[r] + xb[off];
    }
  }
}

// ---------------------------------------------------------------------------
// MFMA flash attention (r12 verbatim — best measured config, 50.2 us):
// K direct-global + XCD chunked swizzle (FETCH 34.9 -> 6.2 MB), V LDS dbuf
// with permuted columns (pb = pk4 verbatim), 1 barrier/iter, SCALAR exp2_fast.
// ---------------------------------------------------------------------------
__global__ __launch_bounds__(512, 4) void attn_mfma_kernel(
    const unsigned char* __restrict__ qT8, const unsigned char* __restrict__ kT8,
    const unsigned char* __restrict__ vv8, unsigned char* __restrict__ aoT8) {
  __shared__ __align__(16) unsigned char kvs[2 * 9216];    // V dbuf fp8
  __shared__ __align__(16) unsigned char st8[4 * 32 * 80]; // epilogue stage fp8
  __shared__ float lbuf[128];
  // XCD-aware swizzle: lid in [0,512); xcd = lid&7 gets blocks [xcd*64, +64)
  int lid = blockIdx.x + 32 * blockIdx.y;
  int swz = (lid & 7) * 64 + (lid >> 3);
  int bh = swz >> 5;
  int b = bh >> 3, h = bh & 7;
  int i0 = (swz & 31) * 128;
  const size_t hb = (size_t)bh * NN_TOK;
  const unsigned char* __restrict__ qtg = qT8 + hb * DHEAD;
  const unsigned char* __restrict__ ktg = kT8 + hb * DHEAD;
  const unsigned char* __restrict__ vg  = vv8 + hb * DHEAD;
  int t = threadIdx.x;
  int w = t >> 6, lane = t & 63, l31 = lane & 31, q1h = lane >> 5;
  int strip = w & 3, parity = w >> 2;
  int iw = i0 + strip * 32;

  const unsigned char* qrow = qtg + (size_t)(iw + l31) * DHEAD + q1h * 32;
  uint4 qv0 = *(const uint4*)(qrow);
  uint4 qv1 = *(const uint4*)(qrow + 16);
  i32x8 qf = {(int)qv0.x, (int)qv0.y, (int)qv0.z, (int)qv0.w,
              (int)qv1.x, (int)qv1.y, (int)qv1.z, (int)qv1.w};
  i32x8 ones;                       // 32x fp8 e4m3 1.0 per lane (A = all-ones)
  #pragma unroll
  for (int i = 0; i < 8; ++i) ones[i] = 0x38383838;

  const unsigned char* kfb = ktg + (size_t)(parity * 64 + l31) * DHEAD + q1h * 32;

  int vtile = t >> 8, vrr = (t >> 2) & 63, vch = t & 3;
  const unsigned char* vga = &vg[(size_t)vrr * NN_TOK + vtile * 64 + vch * 16];
  int vbase = vtile * 4608 + vrr * 72 + 8 * (vch & 1) + 16 * (vch >> 1);

  uint4 vx = *(const uint4*)(vga);   // prologue V load for rt=0

  const f32x16 z16 = {0,0,0,0,0,0,0,0,0,0,0,0,0,0,0,0};
  f32x16 o0 = z16, o1 = z16, lacc = z16;

  int cur = 0;
  for (int rt = 0; rt < NN_TOK / 128; ++rt) {
    int j0 = rt * 128;
    {  // write-late: V tile rt into buffer cur, permuted column placement
      unsigned char* vd = kvs + cur * 9216 + vbase;
      *(uint2*)vd = make_uint2(vx.x, vx.z);          // bit2(j)=0 columns
      *(uint2*)(vd + 32) = make_uint2(vx.y, vx.w);   // bit2(j)=1 columns
    }
    if (rt + 1 < NN_TOK / 128)       // issue-early: next V tile
      vx = *(const uint4*)(vga + (rt + 1) * 128);

    // K fragments direct from global (no barrier dependency; L2-hit via swz)
    i32x8 ka0 = ld_g32(kfb + (size_t)j0 * DHEAD);
    i32x8 ka1 = ld_g32(kfb + (size_t)(j0 + 32) * DHEAD);

    __syncthreads();                 // V[cur] visible; single barrier per iter

    f32x16 s0 = __builtin_amdgcn_mfma_scale_f32_32x32x64_f8f6f4(
        ka0, qf, z16, 0, 0, 0, SC_ONE, 0, SC_ONE);
    f32x16 s1 = __builtin_amdgcn_mfma_scale_f32_32x32x64_f8f6f4(
        ka1, qf, z16, 0, 0, 0, SC_ONE, 0, SC_ONE);

    // fast exp2 (scalar VALU), pack 4 fp8 per dword; l via ones-MFMA below
    unsigned pk4[8];
    #pragma unroll
    for (int g = 0; g < 4; ++g) {
      float p0 = exp2_fast(s0[4 * g + 0]);
      float p1 = exp2_fast(s0[4 * g + 1]);
      float p2 = exp2_fast(s0[4 * g + 2]);
      float p3 = exp2_fast(s0[4 * g + 3]);
      pk4[g] = pk_fp8x4(p0, p1, p2, p3);
    }
    #pragma unroll
    for (int g = 0; g < 4; ++g) {
      float p0 = exp2_fast(s1[4 * g + 0]);
      float p1 = exp2_fast(s1[4 * g + 1]);
      float p2 = exp2_fast(s1[4 * g + 2]);
      float p3 = exp2_fast(s1[4 * g + 3]);
      pk4[4 + g] = pk_fp8x4(p0, p1, p2, p3);
    }

    // P fragment: permuted V -> lane's own packs are its B-fragment verbatim.
    i32x8 pb;
    #pragma unroll
    for (int g = 0; g < 8; ++g) pb[g] = (int)pk4[g];

    // PV + ones-l from LDS V[cur] (columns pre-permuted to match)
    const unsigned char* vsw = kvs + cur * 9216 + parity * 4608;
    i32x8 va0 = ld_frag32(&vsw[l31 * 72 + q1h * 32]);
    i32x8 va1 = ld_frag32(&vsw[(32 + l31) * 72 + q1h * 32]);
    o0 = __builtin_amdgcn_mfma_scale_f32_32x32x64_f8f6f4(
        va0, pb, o0, 0, 0, 0, SC_ONE, 0, SC_ONE);
    o1 = __builtin_amdgcn_mfma_scale_f32_32x32x64_f8f6f4(
        va1, pb, o1, 0, 0, 0, SC_ONE, 0, SC_ONE);
    lacc = __builtin_amdgcn_mfma_scale_f32_32x32x64_f8f6f4(
        ones, pb, lacc, 0, 0, 0, SC_ONE, 0, SC_ONE);
    cur ^= 1;
  }
  float lrun = lacc[0];   // all 32 C-rows equal sum_j P[j][i]

  // ---- two-phase parity combine (obuf overlays V dbuf; st8 separate) ----
  float* obuf = (float*)kvs;           // [strip][d 32][i 32] f32 = 16 KB
  __syncthreads();
  if (parity == 1) {                   // phase A: o0 (d 0..31)
    #pragma unroll
    for (int r = 0; r < 16; ++r) {
      int d = (r & 3) + 8 * (r >> 2) + 4 * q1h;
      obuf[strip * 1024 + d * 32 + l31] = o0[r];
    }
    if (q1h == 0) lbuf[strip * 32 + l31] = lrun;
  }
  __syncthreads();
  if (parity == 0) {
    lrun += lbuf[strip * 32 + l31];
    #pragma unroll
    for (int r = 0; r < 16; ++r) {
      int d = (r & 3) + 8 * (r >> 2) + 4 * q1h;
      o0[r] += obuf[strip * 1024 + d * 32 + l31];
    }
  }
  __syncthreads();
  if (parity == 1) {                   // phase B: o1 (d 32..63)
    #pragma unroll
    for (int r = 0; r < 16; ++r) {
      int d = (r & 3) + 8 * (r >> 2) + 4 * q1h;
      obuf[strip * 1024 + d * 32 + l31] = o1[r];
    }
  }
  __syncthreads();
  if (parity == 0) {
    #pragma unroll
    for (int r = 0; r < 16; ++r) {
      int d = (r & 3) + 8 * (r >> 2) + 4 * q1h;
      o1[r] += obuf[strip * 1024 + d * 32 + l31];
    }
    float inv = 1.0f / lrun;
    unsigned char* stw = st8 + strip * 2560;   // [32 i][80 B]
    #pragma unroll
    for (int dm = 0; dm < 2; ++dm) {
      #pragma unroll
      for (int g = 0; g < 4; ++g) {
        float v0 = ((dm == 0) ? o0[4 * g + 0] : o1[4 * g + 0]) * inv;
        float v1 = ((dm == 0) ? o0[4 * g + 1] : o1[4 * g + 1]) * inv;
        float v2 = ((dm == 0) ? o0[4 * g + 2] : o1[4 * g + 2]) * inv;
        float v3 = ((dm == 0) ? o0[4 * g + 3] : o1[4 * g + 3]) * inv;
        *(unsigned*)&stw[l31 * 80 + dm * 32 + g * 8 + q1h * 4] =
            pk_fp8x4(v0, v1, v2, v3);
      }
    }
    const size_t obase = (size_t)b * NN_TOK;
    #pragma unroll
    for (int it = 0; it < 4; ++it) {
      int idx = it * 64 + lane;
      int row = idx >> 3, ch = idx & 7;      // 32 rows x 8 8B-chunks
      int tok = iw + row;
      *(uint2*)&aoT8[(obase + tok) * HID + h * DHEAD + ch * 8] =
          *(const uint2*)&stw[row * 80 + ch * 8];
    }
  }
}

// ---------------------------------------------------------------------------
extern "C" void kernel_launch(void* const* d_in, const int* in_sizes, int n_in,
                              void* d_out, int out_size, void* d_ws, size_t ws_size,
                              hipStream_t stream) {
  const float* x     = (const float*)d_in[0];
  const float* gamma = (const float*)d_in[1];
  const float* beta  = (const float*)d_in[2];
  const float* wq    = (const float*)d_in[3];
  const float* bq    = (const float*)d_in[4];
  const float* wk    = (const float*)d_in[5];
  const float* bk    = (const float*)d_in[6];
  const float* wv    = (const float*)d_in[7];
  const float* bv    = (const float*)d_in[8];
  const float* wo    = (const float*)d_in[9];
  const float* bo    = (const float*)d_in[10];
  float* out = (float*)d_out;

  const size_t SZ = (size_t)BB * CC * NN_TOK;       // 4,194,304 elements
  const size_t WZ = (size_t)CC * HID;
  unsigned char* xnT8 = (unsigned char*)d_ws;       // fp8 [b][tok][c]     4 MB
  unsigned char* qT8  = xnT8 + SZ;                  // fp8 [b,h,tok,d]     4 MB
  unsigned char* kT8  = qT8 + SZ;                   // fp8                 4 MB
  unsigned char* vB8  = kT8 + SZ;                   // fp8 [b][c][tok]     4 MB
  unsigned char* aoT8 = vB8 + SZ;                   // fp8 [b][tok][hid]   4 MB
  unsigned char* wq8  = aoT8 + SZ;                  // fp8 weights (x32)
  unsigned char* wk8  = wq8 + WZ;
  unsigned char* wv8  = wk8 + WZ;
  unsigned char* wo8  = wv8 + WZ;                   // fp8 (x16)
  float2* gnpart = (float2*)(wo8 + WZ);             // 1024 float2

  gn_stats_wconv_kernel<<<dim3(1024), dim3(256), 0, stream>>>(
      x, gnpart, wq, wk, wv, wo, wq8, wk8, wv8, wo8);

  gn_norm_t_kernel<<<dim3(NN_TOK / 64, CC / 64, BB), dim3(256), 0, stream>>>(
      x, gamma, beta, gnpart, xnT8);

  qkv_gemm_kernel<<<dim3(NN_TOK / 128, 12, BB), dim3(256), 0, stream>>>(
      xnT8, wq8, wk8, wv8, bq, bk, bv, qT8, kT8, vB8);

  attn_mfma_kernel<<<dim3(NN_TOK / 128, BB * HEADS), dim3(512), 0, stream>>>(
      qT8, kT8, vB8, aoT8);

  outproj_kernel<<<dim3(NN_TOK / 64, CC / 64, BB), dim3(256), 0, stream>>>(
      aoT8, wo8, bo, x, out);
}